// Round 5
// baseline (703.335 us; speedup 1.0000x reference)
//
#include <hip/hip_runtime.h>

#define SEQ 2048
#define DMODEL 1024
#define NH 16
#define DK 64
#define NB 4
#define SC2 0.1803368801111204f   // (1/sqrt(64)) * log2(e)

typedef __attribute__((ext_vector_type(4))) float floatx4;
typedef __attribute__((ext_vector_type(8))) short s16x8;
typedef __attribute__((ext_vector_type(4))) short s16x4;
typedef __attribute__((ext_vector_type(8))) unsigned short u16x8;
typedef __attribute__((ext_vector_type(4))) unsigned short u16x4;
typedef __attribute__((ext_vector_type(2))) unsigned int u32x2;

// fp32 -> bf16 round-to-nearest-even
__device__ __forceinline__ unsigned short f2bf(float x) {
    union { float f; unsigned int u; } c; c.f = x;
    unsigned int u = c.u + (0x7fffu + ((c.u >> 16) & 1u));
    return (unsigned short)(u >> 16);
}

// pack two fp32 -> bf16 pair (round-half-up): lo16 = a, hi16 = b. 3 VALU ops.
__device__ __forceinline__ unsigned int pkbf(float a, float b) {
    union { float f; unsigned int u; } ca, cb; ca.f = a; cb.f = b;
    return __builtin_amdgcn_perm(cb.u + 0x8000u, ca.u + 0x8000u, 0x07060302u);
}

__device__ __forceinline__ floatx4 mfma16x16x16bf(s16x4 a, s16x4 b, floatx4 c) {
#if __has_builtin(__builtin_amdgcn_mfma_f32_16x16x16bf16_1k)
    return __builtin_amdgcn_mfma_f32_16x16x16bf16_1k(a, b, c, 0, 0, 0);
#else
    asm volatile("v_mfma_f32_16x16x16_bf16 %0, %1, %2, %0" : "+v"(c) : "v"(a), "v"(b));
    return c;
#endif
}

// async global->LDS, 16B per lane; lds dest = wave-uniform base + lane*16
__device__ __forceinline__ void gll16(const unsigned short* g, unsigned short* l) {
    __builtin_amdgcn_global_load_lds(
        (const __attribute__((address_space(1))) unsigned int*)(const void*)g,
        (__attribute__((address_space(3))) unsigned int*)(void*)l, 16, 0, 0);
}

// ---------------------------------------------------------------------------
// Kernel 0: fp32 -> bf16 conversion for the 3 activations + 4 weights.
// grid (4096, 7), block 256. 8 elems/thread.
// ---------------------------------------------------------------------------
__global__ __launch_bounds__(256)
void cvt7(const float* __restrict__ xq, const float* __restrict__ xk,
          const float* __restrict__ xv, const float* __restrict__ wq,
          const float* __restrict__ wk, const float* __restrict__ wv,
          const float* __restrict__ wo,
          unsigned short* __restrict__ oxq, unsigned short* __restrict__ oxk,
          unsigned short* __restrict__ oxv, unsigned short* __restrict__ owq,
          unsigned short* __restrict__ owk, unsigned short* __restrict__ owv,
          unsigned short* __restrict__ owo)
{
    const int z = blockIdx.y;
    const float* s; unsigned short* d; int n8;
    const int nx8 = (NB * SEQ * DMODEL) / 8, nw8 = (DMODEL * DMODEL) / 8;
    switch (z) {
        case 0: s = xq; d = oxq; n8 = nx8; break;
        case 1: s = xk; d = oxk; n8 = nx8; break;
        case 2: s = xv; d = oxv; n8 = nx8; break;
        case 3: s = wq; d = owq; n8 = nw8; break;
        case 4: s = wk; d = owk; n8 = nw8; break;
        case 5: s = wv; d = owv; n8 = nw8; break;
        default: s = wo; d = owo; n8 = nw8; break;
    }
    const int i = blockIdx.x * 256 + threadIdx.x;
    if (i >= n8) return;
    floatx4 a = ((const floatx4*)s)[2 * i];
    floatx4 b = ((const floatx4*)s)[2 * i + 1];
    u16x8 o = { f2bf(a[0]), f2bf(a[1]), f2bf(a[2]), f2bf(a[3]),
                f2bf(b[0]), f2bf(b[1]), f2bf(b[2]), f2bf(b[3]) };
    ((u16x8*)d)[i] = o;
}

// ---------------------------------------------------------------------------
// Kernel 1: Q/K/V projection, m97-style bf16 NT-GEMM (128x128 tile, BK=32,
// global_load_lds width=16). Block swizzle: XCD = m-tile group (kept from r4:
// saved ~26 us on non-attn time).
//   z=0: Q bf16 [bh][s][64], pre-scaled by SC2
//   z=1: K bf16 [bh][s][64]
//   z=2: V^T bf16 [bh][64][s]
// grid (8, 64, 3), block 256
// ---------------------------------------------------------------------------
__global__ __launch_bounds__(256)
void proj_qkv(const unsigned short* __restrict__ Xq, const unsigned short* __restrict__ Xk,
              const unsigned short* __restrict__ Xv,
              const unsigned short* __restrict__ Wq, const unsigned short* __restrict__ Wk,
              const unsigned short* __restrict__ Wv,
              const float* __restrict__ bq, const float* __restrict__ bk,
              const float* __restrict__ bv,
              unsigned short* __restrict__ Oq, unsigned short* __restrict__ Ok,
              unsigned short* __restrict__ Ovt)
{
    const int z = blockIdx.z;
    const unsigned short* Xp = (z == 0) ? Xq : (z == 1) ? Xk : Xv;
    const unsigned short* Wp = (z == 0) ? Wq : (z == 1) ? Wk : Wv;
    const float* bp = (z == 0) ? bq : (z == 1) ? bk : bv;

    const int tid  = threadIdx.x;
    const int lane = tid & 63;
    const int wave = tid >> 6;
    const int quad = lane >> 4;
    const int lc   = lane & 15;
    const int wm   = (wave >> 1) * 64;
    const int wn   = (wave & 1) * 64;
    // XCD-affinity swizzle: xcd = lin%8; m-tiles with ty%8==xcd stay local
    const int lin = blockIdx.x + 8 * blockIdx.y;
    const int xcd = lin & 7, j = lin >> 3;
    const int m0 = (xcd + 8 * (j & 7)) * 128;
    const int n0 = (j >> 3) * 128;

    __shared__ unsigned short As[128 * 32];  // no padding: global_load_lds layout
    __shared__ unsigned short Bs[128 * 32];  // stride 64B -> 2-way banks (free)

    floatx4 acc[4][4];
#pragma unroll
    for (int i = 0; i < 4; i++)
#pragma unroll
        for (int jj = 0; jj < 4; jj++) acc[i][jj] = (floatx4){0.f, 0.f, 0.f, 0.f};

    const unsigned short* ga = Xp + (size_t)(m0 + (tid >> 2)) * DMODEL + (tid & 3) * 8;
    const unsigned short* gb = Wp + (size_t)(n0 + (tid >> 2)) * DMODEL + (tid & 3) * 8;
    unsigned short* lA = As + wave * 512;   // lane*16B appended by HW
    unsigned short* lB = Bs + wave * 512;

    for (int k0 = 0; k0 < DMODEL; k0 += 32) {
        __syncthreads();
        gll16(ga, lA);
        gll16(ga + 64 * DMODEL, lA + 2048);
        gll16(gb, lB);
        gll16(gb + 64 * DMODEL, lB + 2048);
        ga += 32; gb += 32;
        __syncthreads();

        s16x8 af[4], bf[4];
#pragma unroll
        for (int t = 0; t < 4; t++) {
            af[t] = *(const s16x8*)&As[(wm + t * 16 + lc) * 32 + quad * 8];
            bf[t] = *(const s16x8*)&Bs[(wn + t * 16 + lc) * 32 + quad * 8];
        }
#pragma unroll
        for (int tr = 0; tr < 4; tr++)
#pragma unroll
            for (int tc = 0; tc < 4; tc++)
                acc[tr][tc] = __builtin_amdgcn_mfma_f32_16x16x32_bf16(
                    af[tr], bf[tc], acc[tr][tc], 0, 0, 0);
    }

    if (z < 2) {
        unsigned short* Op = (z == 0) ? Oq : Ok;
        const float sc = (z == 0) ? SC2 : 1.0f;
#pragma unroll
        for (int tc = 0; tc < 4; tc++) {
            const int n = n0 + wn + tc * 16 + lc;
            const float bias = bp[n];
            const int h = n >> 6, dd = n & 63;
#pragma unroll
            for (int tr = 0; tr < 4; tr++) {
#pragma unroll
                for (int r = 0; r < 4; r++) {
                    const int m = m0 + wm + tr * 16 + quad * 4 + r;
                    const int b = m >> 11, s = m & (SEQ - 1);
                    Op[((size_t)(b * NH + h) * SEQ + s) * DK + dd] =
                        f2bf((acc[tr][tc][r] + bias) * sc);
                }
            }
        }
    } else {
        // V^T: [bh][d][s]; 4 r-values are s-consecutive -> packed 8B stores
#pragma unroll
        for (int tc = 0; tc < 4; tc++) {
            const int n = n0 + wn + tc * 16 + lc;
            const float bias = bp[n];
            const int h = n >> 6, dd = n & 63;
#pragma unroll
            for (int tr = 0; tr < 4; tr++) {
                const int m = m0 + wm + tr * 16 + quad * 4;
                const int b = m >> 11, s = m & (SEQ - 1);
                u16x4 pv = { f2bf(acc[tr][tc][0] + bias), f2bf(acc[tr][tc][1] + bias),
                             f2bf(acc[tr][tc][2] + bias), f2bf(acc[tr][tc][3] + bias) };
                *(u16x4*)&Ovt[((size_t)(b * NH + h) * DK + dd) * SEQ + s] = pv;
            }
        }
    }
}

// ---------------------------------------------------------------------------
// Kernel 2: attention, zero-LDS zero-barrier. 32 q-rows/wave (mt=2), grid
// doubled to 1024 blocks -> 4 blocks/CU = 16 waves/CU (TLP latency hiding,
// no register double-buffer: r4's KVt ping-pong spilled -> 401 MB scratch).
// PV MFMAs fused into the per-nt score loop (pj live set 16 -> 4 regs).
// XCD-affinity swizzle: 8 heads per XCD -> K/V working set 4 MB = L2.
// grid (16, 64), block 256
// ---------------------------------------------------------------------------
__global__ __launch_bounds__(256, 4)
void attn2(const unsigned short* __restrict__ Qg, const unsigned short* __restrict__ Kg,
           const unsigned short* __restrict__ Vt, unsigned short* __restrict__ Og)
{
    // swizzle: lin%8 selects XCD (round-robin dispatch); give each XCD 8 heads
    const int lin = blockIdx.x + 16 * blockIdx.y;
    const int xcd = lin & 7, j = lin >> 3;
    const int bh  = xcd * 8 + (j & 7);   // 8 heads per XCD
    const int qt  = j >> 3;              // q-block 0..15 (128 rows each)
    const int b = bh >> 4, h = bh & 15;

    const int lane = threadIdx.x & 63;
    const int wave = threadIdx.x >> 6;
    const int quad = lane >> 4;
    const int lc   = lane & 15;
    const int q0   = qt * 128 + wave * 32;

    const unsigned short* Qp = Qg + (size_t)bh * SEQ * DK;
    const unsigned short* Kp = Kg + (size_t)bh * SEQ * DK;
    const unsigned short* Vp = Vt + (size_t)bh * DK * SEQ;

    // Q B-frags (16x16x32): [q-tile mt][k-chunk], loaded once
    s16x8 qf[2][2];
#pragma unroll
    for (int mt = 0; mt < 2; mt++)
#pragma unroll
        for (int kc = 0; kc < 2; kc++)
            qf[mt][kc] = *(const s16x8*)&Qp[(size_t)(q0 + mt * 16 + lc) * DK + kc * 32 + quad * 8];

    floatx4 oacc[4][2];   // O^T tiles [dt][mt]
    float rs[2] = {0.f, 0.f};
#pragma unroll
    for (int dt = 0; dt < 4; dt++)
#pragma unroll
        for (int mt = 0; mt < 2; mt++) oacc[dt][mt] = (floatx4){0.f, 0.f, 0.f, 0.f};

    for (int kv0 = 0; kv0 < SEQ; kv0 += 64) {
        // V^T A-frags (16x16x16): [dt][kv-chunk] — issue all early
        s16x4 vf[4][4];
#pragma unroll
        for (int dt = 0; dt < 4; dt++)
#pragma unroll
            for (int kc4 = 0; kc4 < 4; kc4++)
                vf[dt][kc4] = *(const s16x4*)&Vp[(size_t)(dt * 16 + lc) * SEQ + kv0 + kc4 * 16 + quad * 4];

        // per 16-row kv-chunk: scores -> exp2 -> pack -> PV (fused, small live set)
#pragma unroll
        for (int nt = 0; nt < 4; nt++) {
            s16x8 kf0 = *(const s16x8*)&Kp[(size_t)(kv0 + nt * 16 + lc) * DK + quad * 8];
            s16x8 kf1 = *(const s16x8*)&Kp[(size_t)(kv0 + nt * 16 + lc) * DK + 32 + quad * 8];
            floatx4 sc[2];
#pragma unroll
            for (int mt = 0; mt < 2; mt++) {
                sc[mt] = __builtin_amdgcn_mfma_f32_16x16x32_bf16(
                    kf0, qf[mt][0], (floatx4){0.f, 0.f, 0.f, 0.f}, 0, 0, 0);
                sc[mt] = __builtin_amdgcn_mfma_f32_16x16x32_bf16(
                    kf1, qf[mt][1], sc[mt], 0, 0, 0);
            }
            unsigned int pj[2][2];
#pragma unroll
            for (int mt = 0; mt < 2; mt++) {
                float e0 = __builtin_amdgcn_exp2f(sc[mt][0]);
                float e1 = __builtin_amdgcn_exp2f(sc[mt][1]);
                float e2 = __builtin_amdgcn_exp2f(sc[mt][2]);
                float e3 = __builtin_amdgcn_exp2f(sc[mt][3]);
                rs[mt] += (e0 + e1) + (e2 + e3);
                pj[mt][0] = pkbf(e0, e1);
                pj[mt][1] = pkbf(e2, e3);
            }
#pragma unroll
            for (int dt = 0; dt < 4; dt++)
#pragma unroll
                for (int mt = 0; mt < 2; mt++)
                    oacc[dt][mt] = mfma16x16x16bf(
                        vf[dt][nt], *(const s16x4*)&pj[mt][0], oacc[dt][mt]);
        }
    }

    // finish row sums across quads (lanes with equal lc hold same q columns)
    float inv[2];
#pragma unroll
    for (int mt = 0; mt < 2; mt++) {
        float r = rs[mt];
        r += __shfl_xor(r, 16);
        r += __shfl_xor(r, 32);
        inv[mt] = __builtin_amdgcn_rcpf(r);
    }

    // store O^T -> X[b][s][h*64+d] bf16 (packed 8B stores)
#pragma unroll
    for (int mt = 0; mt < 2; mt++) {
        const int s = q0 + mt * 16 + lc;
        const size_t base = ((size_t)(b * SEQ + s)) * DMODEL + h * DK;
#pragma unroll
        for (int dt = 0; dt < 4; dt++) {
            float v0 = oacc[dt][mt][0] * inv[mt];
            float v1 = oacc[dt][mt][1] * inv[mt];
            float v2 = oacc[dt][mt][2] * inv[mt];
            float v3 = oacc[dt][mt][3] * inv[mt];
            u32x2 pk = { pkbf(v0, v1), pkbf(v2, v3) };
            *(u32x2*)&Og[base + dt * 16 + quad * 4] = pk;
        }
    }
}

// ---------------------------------------------------------------------------
// Kernel 3: out = X @ Wo^T + bo, fp32 output. m97-style bf16 NT-GEMM.
// grid (8, 64), block 256
// ---------------------------------------------------------------------------
__global__ __launch_bounds__(256)
void out_proj(const unsigned short* __restrict__ Xg, const unsigned short* __restrict__ Wo,
              const float* __restrict__ bo, float* __restrict__ Out)
{
    const int tid  = threadIdx.x;
    const int lane = tid & 63;
    const int wave = tid >> 6;
    const int quad = lane >> 4;
    const int lc   = lane & 15;
    const int wm   = (wave >> 1) * 64;
    const int wn   = (wave & 1) * 64;
    const int lin = blockIdx.x + 8 * blockIdx.y;
    const int xcd = lin & 7, j = lin >> 3;
    const int m0 = (xcd + 8 * (j & 7)) * 128;
    const int n0 = (j >> 3) * 128;

    __shared__ unsigned short As[128 * 32];
    __shared__ unsigned short Bs[128 * 32];

    floatx4 acc[4][4];
#pragma unroll
    for (int i = 0; i < 4; i++)
#pragma unroll
        for (int jj = 0; jj < 4; jj++) acc[i][jj] = (floatx4){0.f, 0.f, 0.f, 0.f};

    const unsigned short* ga = Xg + (size_t)(m0 + (tid >> 2)) * DMODEL + (tid & 3) * 8;
    const unsigned short* gb = Wo + (size_t)(n0 + (tid >> 2)) * DMODEL + (tid & 3) * 8;
    unsigned short* lA = As + wave * 512;
    unsigned short* lB = Bs + wave * 512;

    for (int k0 = 0; k0 < DMODEL; k0 += 32) {
        __syncthreads();
        gll16(ga, lA);
        gll16(ga + 64 * DMODEL, lA + 2048);
        gll16(gb, lB);
        gll16(gb + 64 * DMODEL, lB + 2048);
        ga += 32; gb += 32;
        __syncthreads();

        s16x8 af[4], bf[4];
#pragma unroll
        for (int t = 0; t < 4; t++) {
            af[t] = *(const s16x8*)&As[(wm + t * 16 + lc) * 32 + quad * 8];
            bf[t] = *(const s16x8*)&Bs[(wn + t * 16 + lc) * 32 + quad * 8];
        }
#pragma unroll
        for (int tr = 0; tr < 4; tr++)
#pragma unroll
            for (int tc = 0; tc < 4; tc++)
                acc[tr][tc] = __builtin_amdgcn_mfma_f32_16x16x32_bf16(
                    af[tr], bf[tc], acc[tr][tc], 0, 0, 0);
    }

#pragma unroll
    for (int tc = 0; tc < 4; tc++) {
        const int n = n0 + wn + tc * 16 + lc;
        const float bias = bo[n];
#pragma unroll
        for (int tr = 0; tr < 4; tr++) {
#pragma unroll
            for (int r = 0; r < 4; r++) {
                const int m = m0 + wm + tr * 16 + quad * 4 + r;
                Out[(size_t)m * DMODEL + n] = acc[tr][tc][r] + bias;
            }
        }
    }
}

// ---------------------------------------------------------------------------
extern "C" void kernel_launch(void* const* d_in, const int* in_sizes, int n_in,
                              void* d_out, int out_size, void* d_ws, size_t ws_size,
                              hipStream_t stream)
{
    const float* q  = (const float*)d_in[0];
    const float* k  = (const float*)d_in[1];
    const float* v  = (const float*)d_in[2];
    const float* Wq = (const float*)d_in[3];
    const float* bq = (const float*)d_in[4];
    const float* Wk = (const float*)d_in[5];
    const float* bk = (const float*)d_in[6];
    const float* Wv = (const float*)d_in[7];
    const float* bv = (const float*)d_in[8];
    const float* Wo = (const float*)d_in[9];
    const float* bo = (const float*)d_in[10];

    const size_t NX = (size_t)NB * SEQ * DMODEL;   // 8,388,608
    const size_t NW = (size_t)DMODEL * DMODEL;     // 1,048,576
    unsigned short* xq_bf = (unsigned short*)d_ws;
    unsigned short* xk_bf = xq_bf + NX;
    unsigned short* xv_bf = xk_bf + NX;
    unsigned short* wq_bf = xv_bf + NX;
    unsigned short* wk_bf = wq_bf + NW;
    unsigned short* wv_bf = wk_bf + NW;
    unsigned short* wo_bf = wv_bf + NW;
    unsigned short* Qb    = wo_bf + NW;
    unsigned short* Kb    = Qb + NX;
    unsigned short* Vtb   = Kb + NX;
    unsigned short* Xa    = xq_bf;   // alias: xq_bf dead after proj_qkv
    // footprint: 3*NX + 4*NW + 3*NX = 104 MB

    dim3 blk(256);
    cvt7<<<dim3(4096, 7), blk, 0, stream>>>(q, k, v, Wq, Wk, Wv, Wo,
                                            xq_bf, xk_bf, xv_bf,
                                            wq_bf, wk_bf, wv_bf, wo_bf);
    proj_qkv<<<dim3(8, 64, 3), blk, 0, stream>>>(xq_bf, xk_bf, xv_bf,
                                                 wq_bf, wk_bf, wv_bf,
                                                 bq, bk, bv, Qb, Kb, Vtb);
    attn2<<<dim3(16, 64), blk, 0, stream>>>(Qb, Kb, Vtb, Xa);
    out_proj<<<dim3(8, 64), blk, 0, stream>>>(Xa, wo_bf, bo, (float*)d_out);
}

// Round 6
// 439.468 us; speedup vs baseline: 1.6004x; 1.6004x over previous
//
#include <hip/hip_runtime.h>

#define SEQ 2048
#define DMODEL 1024
#define NH 16
#define DK 64
#define NB 4
#define SC2 0.1803368801111204f   // (1/sqrt(64)) * log2(e)

typedef __attribute__((ext_vector_type(4))) float floatx4;
typedef __attribute__((ext_vector_type(8))) short s16x8;
typedef __attribute__((ext_vector_type(4))) short s16x4;
typedef __attribute__((ext_vector_type(8))) unsigned short u16x8;
typedef __attribute__((ext_vector_type(4))) unsigned short u16x4;
typedef __attribute__((ext_vector_type(2))) unsigned int u32x2;

// fp32 -> bf16 round-to-nearest-even
__device__ __forceinline__ unsigned short f2bf(float x) {
    union { float f; unsigned int u; } c; c.f = x;
    unsigned int u = c.u + (0x7fffu + ((c.u >> 16) & 1u));
    return (unsigned short)(u >> 16);
}

// pack two fp32 -> bf16 pair (round-half-up): lo16 = a, hi16 = b. 3 VALU ops.
__device__ __forceinline__ unsigned int pkbf(float a, float b) {
    union { float f; unsigned int u; } ca, cb; ca.f = a; cb.f = b;
    return __builtin_amdgcn_perm(cb.u + 0x8000u, ca.u + 0x8000u, 0x07060302u);
}

__device__ __forceinline__ floatx4 mfma16x16x16bf(s16x4 a, s16x4 b, floatx4 c) {
#if __has_builtin(__builtin_amdgcn_mfma_f32_16x16x16bf16_1k)
    return __builtin_amdgcn_mfma_f32_16x16x16bf16_1k(a, b, c, 0, 0, 0);
#else
    asm volatile("v_mfma_f32_16x16x16_bf16 %0, %1, %2, %0" : "+v"(c) : "v"(a), "v"(b));
    return c;
#endif
}

// async global->LDS, 16B per lane; lds dest = wave-uniform base + lane*16
__device__ __forceinline__ void gll16(const unsigned short* g, unsigned short* l) {
    __builtin_amdgcn_global_load_lds(
        (const __attribute__((address_space(1))) unsigned int*)(const void*)g,
        (__attribute__((address_space(3))) unsigned int*)(void*)l, 16, 0, 0);
}

// ---------------------------------------------------------------------------
// Kernel 0: fp32 -> bf16 conversion for the 3 activations + 4 weights.
// grid (4096, 7), block 256. 8 elems/thread.
// ---------------------------------------------------------------------------
__global__ __launch_bounds__(256)
void cvt7(const float* __restrict__ xq, const float* __restrict__ xk,
          const float* __restrict__ xv, const float* __restrict__ wq,
          const float* __restrict__ wk, const float* __restrict__ wv,
          const float* __restrict__ wo,
          unsigned short* __restrict__ oxq, unsigned short* __restrict__ oxk,
          unsigned short* __restrict__ oxv, unsigned short* __restrict__ owq,
          unsigned short* __restrict__ owk, unsigned short* __restrict__ owv,
          unsigned short* __restrict__ owo)
{
    const int z = blockIdx.y;
    const float* s; unsigned short* d; int n8;
    const int nx8 = (NB * SEQ * DMODEL) / 8, nw8 = (DMODEL * DMODEL) / 8;
    switch (z) {
        case 0: s = xq; d = oxq; n8 = nx8; break;
        case 1: s = xk; d = oxk; n8 = nx8; break;
        case 2: s = xv; d = oxv; n8 = nx8; break;
        case 3: s = wq; d = owq; n8 = nw8; break;
        case 4: s = wk; d = owk; n8 = nw8; break;
        case 5: s = wv; d = owv; n8 = nw8; break;
        default: s = wo; d = owo; n8 = nw8; break;
    }
    const int i = blockIdx.x * 256 + threadIdx.x;
    if (i >= n8) return;
    floatx4 a = ((const floatx4*)s)[2 * i];
    floatx4 b = ((const floatx4*)s)[2 * i + 1];
    u16x8 o = { f2bf(a[0]), f2bf(a[1]), f2bf(a[2]), f2bf(a[3]),
                f2bf(b[0]), f2bf(b[1]), f2bf(b[2]), f2bf(b[3]) };
    ((u16x8*)d)[i] = o;
}

// ---------------------------------------------------------------------------
// Kernel 1: Q/K/V projection, m97-style bf16 NT-GEMM (128x128 tile, BK=32,
// global_load_lds width=16). XCD-affinity swizzle on m-tiles (kept from r4).
//   z=0: Q bf16 [bh][s][64], pre-scaled by SC2
//   z=1: K bf16 [bh][s][64]
//   z=2: V^T bf16 [bh][64][s]
// grid (8, 64, 3), block 256
// ---------------------------------------------------------------------------
__global__ __launch_bounds__(256)
void proj_qkv(const unsigned short* __restrict__ Xq, const unsigned short* __restrict__ Xk,
              const unsigned short* __restrict__ Xv,
              const unsigned short* __restrict__ Wq, const unsigned short* __restrict__ Wk,
              const unsigned short* __restrict__ Wv,
              const float* __restrict__ bq, const float* __restrict__ bk,
              const float* __restrict__ bv,
              unsigned short* __restrict__ Oq, unsigned short* __restrict__ Ok,
              unsigned short* __restrict__ Ovt)
{
    const int z = blockIdx.z;
    const unsigned short* Xp = (z == 0) ? Xq : (z == 1) ? Xk : Xv;
    const unsigned short* Wp = (z == 0) ? Wq : (z == 1) ? Wk : Wv;
    const float* bp = (z == 0) ? bq : (z == 1) ? bk : bv;

    const int tid  = threadIdx.x;
    const int lane = tid & 63;
    const int wave = tid >> 6;
    const int quad = lane >> 4;
    const int lc   = lane & 15;
    const int wm   = (wave >> 1) * 64;
    const int wn   = (wave & 1) * 64;
    // XCD-affinity swizzle: xcd = lin%8; m-tiles with ty%8==xcd stay local
    const int lin = blockIdx.x + 8 * blockIdx.y;
    const int xcd = lin & 7, j = lin >> 3;
    const int m0 = (xcd + 8 * (j & 7)) * 128;
    const int n0 = (j >> 3) * 128;

    __shared__ unsigned short As[128 * 32];  // no padding: global_load_lds layout
    __shared__ unsigned short Bs[128 * 32];  // stride 64B -> 2-way banks (free)

    floatx4 acc[4][4];
#pragma unroll
    for (int i = 0; i < 4; i++)
#pragma unroll
        for (int jj = 0; jj < 4; jj++) acc[i][jj] = (floatx4){0.f, 0.f, 0.f, 0.f};

    const unsigned short* ga = Xp + (size_t)(m0 + (tid >> 2)) * DMODEL + (tid & 3) * 8;
    const unsigned short* gb = Wp + (size_t)(n0 + (tid >> 2)) * DMODEL + (tid & 3) * 8;
    unsigned short* lA = As + wave * 512;   // lane*16B appended by HW
    unsigned short* lB = Bs + wave * 512;

    for (int k0 = 0; k0 < DMODEL; k0 += 32) {
        __syncthreads();
        gll16(ga, lA);
        gll16(ga + 64 * DMODEL, lA + 2048);
        gll16(gb, lB);
        gll16(gb + 64 * DMODEL, lB + 2048);
        ga += 32; gb += 32;
        __syncthreads();

        s16x8 af[4], bf[4];
#pragma unroll
        for (int t = 0; t < 4; t++) {
            af[t] = *(const s16x8*)&As[(wm + t * 16 + lc) * 32 + quad * 8];
            bf[t] = *(const s16x8*)&Bs[(wn + t * 16 + lc) * 32 + quad * 8];
        }
#pragma unroll
        for (int tr = 0; tr < 4; tr++)
#pragma unroll
            for (int tc = 0; tc < 4; tc++)
                acc[tr][tc] = __builtin_amdgcn_mfma_f32_16x16x32_bf16(
                    af[tr], bf[tc], acc[tr][tc], 0, 0, 0);
    }

    if (z < 2) {
        unsigned short* Op = (z == 0) ? Oq : Ok;
        const float sc = (z == 0) ? SC2 : 1.0f;
#pragma unroll
        for (int tc = 0; tc < 4; tc++) {
            const int n = n0 + wn + tc * 16 + lc;
            const float bias = bp[n];
            const int h = n >> 6, dd = n & 63;
#pragma unroll
            for (int tr = 0; tr < 4; tr++) {
#pragma unroll
                for (int r = 0; r < 4; r++) {
                    const int m = m0 + wm + tr * 16 + quad * 4 + r;
                    const int b = m >> 11, s = m & (SEQ - 1);
                    Op[((size_t)(b * NH + h) * SEQ + s) * DK + dd] =
                        f2bf((acc[tr][tc][r] + bias) * sc);
                }
            }
        }
    } else {
        // V^T: [bh][d][s]; 4 r-values are s-consecutive -> packed 8B stores
#pragma unroll
        for (int tc = 0; tc < 4; tc++) {
            const int n = n0 + wn + tc * 16 + lc;
            const float bias = bp[n];
            const int h = n >> 6, dd = n & 63;
#pragma unroll
            for (int tr = 0; tr < 4; tr++) {
                const int m = m0 + wm + tr * 16 + quad * 4;
                const int b = m >> 11, s = m & (SEQ - 1);
                u16x4 pv = { f2bf(acc[tr][tc][0] + bias), f2bf(acc[tr][tc][1] + bias),
                             f2bf(acc[tr][tc][2] + bias), f2bf(acc[tr][tc][3] + bias) };
                *(u16x4*)&Ovt[((size_t)(b * NH + h) * DK + dd) * SEQ + s] = pv;
            }
        }
    }
}

// ---------------------------------------------------------------------------
// Kernel 2: attention — r3's proven structure (64 q-rows/wave, register P path,
// VGPR 116, no spill) + XCD head-affinity swizzle (8 heads/XCD -> K/V working
// set 4 MB = per-XCD L2). No register double-buffer, no occupancy forcing:
// r4 (KVt ping-pong) and r5 (launch_bounds 4) both spilled -> 300-400 MB
// scratch traffic. DO NOT raise register pressure in this kernel.
// grid (8, 64), block 256
// ---------------------------------------------------------------------------
__global__ __launch_bounds__(256, 2)
void attn2(const unsigned short* __restrict__ Qg, const unsigned short* __restrict__ Kg,
           const unsigned short* __restrict__ Vt, unsigned short* __restrict__ Og)
{
    // swizzle: lin%8 selects XCD (round-robin dispatch); give each XCD 8 heads
    const int lin = blockIdx.x + 8 * blockIdx.y;
    const int xcd = lin & 7, j = lin >> 3;
    const int bh  = xcd * 8 + (j & 7);   // 8 heads per XCD
    const int qt  = j >> 3;              // q-block 0..7 (256 rows each)
    const int b = bh >> 4, h = bh & 15;

    const int lane = threadIdx.x & 63;
    const int wave = threadIdx.x >> 6;
    const int quad = lane >> 4;
    const int lc   = lane & 15;
    const int q0   = qt * 256 + wave * 64;

    const unsigned short* Qp = Qg + (size_t)bh * SEQ * DK;
    const unsigned short* Kp = Kg + (size_t)bh * SEQ * DK;
    const unsigned short* Vp = Vt + (size_t)bh * DK * SEQ;

    // Q B-frags (16x16x32): [q-tile mt][k-chunk], loaded once
    s16x8 qf[4][2];
#pragma unroll
    for (int mt = 0; mt < 4; mt++)
#pragma unroll
        for (int kc = 0; kc < 2; kc++)
            qf[mt][kc] = *(const s16x8*)&Qp[(size_t)(q0 + mt * 16 + lc) * DK + kc * 32 + quad * 8];

    floatx4 oacc[4][4];   // O^T tiles [dt][mt]
    float rs[4] = {0.f, 0.f, 0.f, 0.f};
#pragma unroll
    for (int dt = 0; dt < 4; dt++)
#pragma unroll
        for (int mt = 0; mt < 4; mt++) oacc[dt][mt] = (floatx4){0.f, 0.f, 0.f, 0.f};

    for (int kv0 = 0; kv0 < SEQ; kv0 += 64) {
        // K A-frags (16x16x32): [kv-tile nt][k-chunk]
        s16x8 kf[4][2];
#pragma unroll
        for (int nt = 0; nt < 4; nt++)
#pragma unroll
            for (int kc = 0; kc < 2; kc++)
                kf[nt][kc] = *(const s16x8*)&Kp[(size_t)(kv0 + nt * 16 + lc) * DK + kc * 32 + quad * 8];

        // V^T A-frags (16x16x16): [dt][kv-chunk kc4] (issued early, used after exp)
        s16x4 vf[4][4];
#pragma unroll
        for (int dt = 0; dt < 4; dt++)
#pragma unroll
            for (int kc4 = 0; kc4 < 4; kc4++)
                vf[dt][kc4] = *(const s16x4*)&Vp[(size_t)(dt * 16 + lc) * SEQ + kv0 + kc4 * 16 + quad * 4];

        // per kv-tile: scores, exp2, pack P^T B-frags
        unsigned int pj[4][4][2];   // [kv-chunk][q-tile][2]
#pragma unroll
        for (int nt = 0; nt < 4; nt++) {
            floatx4 sc[4];
#pragma unroll
            for (int mt = 0; mt < 4; mt++) sc[mt] = (floatx4){0.f, 0.f, 0.f, 0.f};
#pragma unroll
            for (int kc = 0; kc < 2; kc++)
#pragma unroll
                for (int mt = 0; mt < 4; mt++)
                    sc[mt] = __builtin_amdgcn_mfma_f32_16x16x32_bf16(
                        kf[nt][kc], qf[mt][kc], sc[mt], 0, 0, 0);
#pragma unroll
            for (int mt = 0; mt < 4; mt++) {
                float e0 = __builtin_amdgcn_exp2f(sc[mt][0]);
                float e1 = __builtin_amdgcn_exp2f(sc[mt][1]);
                float e2 = __builtin_amdgcn_exp2f(sc[mt][2]);
                float e3 = __builtin_amdgcn_exp2f(sc[mt][3]);
                rs[mt] += (e0 + e1) + (e2 + e3);
                pj[nt][mt][0] = pkbf(e0, e1);
                pj[nt][mt][1] = pkbf(e2, e3);
            }
        }

        // O^T += V^T P^T  (B operand direct from registers)
#pragma unroll
        for (int kc4 = 0; kc4 < 4; kc4++)
#pragma unroll
            for (int dt = 0; dt < 4; dt++)
#pragma unroll
                for (int mt = 0; mt < 4; mt++)
                    oacc[dt][mt] = mfma16x16x16bf(
                        vf[dt][kc4], *(const s16x4*)&pj[kc4][mt][0], oacc[dt][mt]);
    }

    // finish row sums across quads (lanes with equal lc hold same q columns)
    float inv[4];
#pragma unroll
    for (int mt = 0; mt < 4; mt++) {
        float r = rs[mt];
        r += __shfl_xor(r, 16);
        r += __shfl_xor(r, 32);
        inv[mt] = __builtin_amdgcn_rcpf(r);
    }

    // store O^T -> X[b][s][h*64+d] bf16 (packed 8B stores)
#pragma unroll
    for (int mt = 0; mt < 4; mt++) {
        const int s = q0 + mt * 16 + lc;
        const size_t base = ((size_t)(b * SEQ + s)) * DMODEL + h * DK;
#pragma unroll
        for (int dt = 0; dt < 4; dt++) {
            float v0 = oacc[dt][mt][0] * inv[mt];
            float v1 = oacc[dt][mt][1] * inv[mt];
            float v2 = oacc[dt][mt][2] * inv[mt];
            float v3 = oacc[dt][mt][3] * inv[mt];
            u32x2 pk = { pkbf(v0, v1), pkbf(v2, v3) };
            *(u32x2*)&Og[base + dt * 16 + quad * 4] = pk;
        }
    }
}

// ---------------------------------------------------------------------------
// Kernel 3: out = X @ Wo^T + bo, fp32 output. m97-style bf16 NT-GEMM.
// grid (8, 64), block 256
// ---------------------------------------------------------------------------
__global__ __launch_bounds__(256)
void out_proj(const unsigned short* __restrict__ Xg, const unsigned short* __restrict__ Wo,
              const float* __restrict__ bo, float* __restrict__ Out)
{
    const int tid  = threadIdx.x;
    const int lane = tid & 63;
    const int wave = tid >> 6;
    const int quad = lane >> 4;
    const int lc   = lane & 15;
    const int wm   = (wave >> 1) * 64;
    const int wn   = (wave & 1) * 64;
    const int lin = blockIdx.x + 8 * blockIdx.y;
    const int xcd = lin & 7, j = lin >> 3;
    const int m0 = (xcd + 8 * (j & 7)) * 128;
    const int n0 = (j >> 3) * 128;

    __shared__ unsigned short As[128 * 32];
    __shared__ unsigned short Bs[128 * 32];

    floatx4 acc[4][4];
#pragma unroll
    for (int i = 0; i < 4; i++)
#pragma unroll
        for (int jj = 0; jj < 4; jj++) acc[i][jj] = (floatx4){0.f, 0.f, 0.f, 0.f};

    const unsigned short* ga = Xg + (size_t)(m0 + (tid >> 2)) * DMODEL + (tid & 3) * 8;
    const unsigned short* gb = Wo + (size_t)(n0 + (tid >> 2)) * DMODEL + (tid & 3) * 8;
    unsigned short* lA = As + wave * 512;
    unsigned short* lB = Bs + wave * 512;

    for (int k0 = 0; k0 < DMODEL; k0 += 32) {
        __syncthreads();
        gll16(ga, lA);
        gll16(ga + 64 * DMODEL, lA + 2048);
        gll16(gb, lB);
        gll16(gb + 64 * DMODEL, lB + 2048);
        ga += 32; gb += 32;
        __syncthreads();

        s16x8 af[4], bf[4];
#pragma unroll
        for (int t = 0; t < 4; t++) {
            af[t] = *(const s16x8*)&As[(wm + t * 16 + lc) * 32 + quad * 8];
            bf[t] = *(const s16x8*)&Bs[(wn + t * 16 + lc) * 32 + quad * 8];
        }
#pragma unroll
        for (int tr = 0; tr < 4; tr++)
#pragma unroll
            for (int tc = 0; tc < 4; tc++)
                acc[tr][tc] = __builtin_amdgcn_mfma_f32_16x16x32_bf16(
                    af[tr], bf[tc], acc[tr][tc], 0, 0, 0);
    }

#pragma unroll
    for (int tc = 0; tc < 4; tc++) {
        const int n = n0 + wn + tc * 16 + lc;
        const float bias = bo[n];
#pragma unroll
        for (int tr = 0; tr < 4; tr++) {
#pragma unroll
            for (int r = 0; r < 4; r++) {
                const int m = m0 + wm + tr * 16 + quad * 4 + r;
                Out[(size_t)m * DMODEL + n] = acc[tr][tc][r] + bias;
            }
        }
    }
}

// ---------------------------------------------------------------------------
extern "C" void kernel_launch(void* const* d_in, const int* in_sizes, int n_in,
                              void* d_out, int out_size, void* d_ws, size_t ws_size,
                              hipStream_t stream)
{
    const float* q  = (const float*)d_in[0];
    const float* k  = (const float*)d_in[1];
    const float* v  = (const float*)d_in[2];
    const float* Wq = (const float*)d_in[3];
    const float* bq = (const float*)d_in[4];
    const float* Wk = (const float*)d_in[5];
    const float* bk = (const float*)d_in[6];
    const float* Wv = (const float*)d_in[7];
    const float* bv = (const float*)d_in[8];
    const float* Wo = (const float*)d_in[9];
    const float* bo = (const float*)d_in[10];

    const size_t NX = (size_t)NB * SEQ * DMODEL;   // 8,388,608
    const size_t NW = (size_t)DMODEL * DMODEL;     // 1,048,576
    unsigned short* xq_bf = (unsigned short*)d_ws;
    unsigned short* xk_bf = xq_bf + NX;
    unsigned short* xv_bf = xk_bf + NX;
    unsigned short* wq_bf = xv_bf + NX;
    unsigned short* wk_bf = wq_bf + NW;
    unsigned short* wv_bf = wk_bf + NW;
    unsigned short* wo_bf = wv_bf + NW;
    unsigned short* Qb    = wo_bf + NW;
    unsigned short* Kb    = Qb + NX;
    unsigned short* Vtb   = Kb + NX;
    unsigned short* Xa    = xq_bf;   // alias: xq_bf dead after proj_qkv
    // footprint: 3*NX + 4*NW + 3*NX = 104 MB

    dim3 blk(256);
    cvt7<<<dim3(4096, 7), blk, 0, stream>>>(q, k, v, Wq, Wk, Wv, Wo,
                                            xq_bf, xk_bf, xv_bf,
                                            wq_bf, wk_bf, wv_bf, wo_bf);
    proj_qkv<<<dim3(8, 64, 3), blk, 0, stream>>>(xq_bf, xk_bf, xv_bf,
                                                 wq_bf, wk_bf, wv_bf,
                                                 bq, bk, bv, Qb, Kb, Vtb);
    attn2<<<dim3(8, 64), blk, 0, stream>>>(Qb, Kb, Vtb, Xa);
    out_proj<<<dim3(8, 64), blk, 0, stream>>>(Xa, wo_bf, bo, (float*)d_out);
}

// Round 7
// 345.817 us; speedup vs baseline: 2.0338x; 1.2708x over previous
//
#include <hip/hip_runtime.h>

#define SEQ 2048
#define DMODEL 1024
#define NH 16
#define DK 64
#define NB 4
#define SC2 0.1803368801111204f   // (1/sqrt(64)) * log2(e)

typedef __attribute__((ext_vector_type(4))) float floatx4;
typedef __attribute__((ext_vector_type(8))) short s16x8;
typedef __attribute__((ext_vector_type(4))) short s16x4;
typedef __attribute__((ext_vector_type(8))) unsigned short u16x8;
typedef __attribute__((ext_vector_type(4))) unsigned short u16x4;
typedef __attribute__((ext_vector_type(2))) unsigned int u32x2;

// fp32 -> bf16 round-to-nearest-even
__device__ __forceinline__ unsigned short f2bf(float x) {
    union { float f; unsigned int u; } c; c.f = x;
    unsigned int u = c.u + (0x7fffu + ((c.u >> 16) & 1u));
    return (unsigned short)(u >> 16);
}

// pack two fp32 -> bf16 pair (round-half-up): lo16 = a, hi16 = b. 3 VALU ops.
__device__ __forceinline__ unsigned int pkbf(float a, float b) {
    union { float f; unsigned int u; } ca, cb; ca.f = a; cb.f = b;
    return __builtin_amdgcn_perm(cb.u + 0x8000u, ca.u + 0x8000u, 0x07060302u);
}

__device__ __forceinline__ floatx4 mfma16x16x16bf(s16x4 a, s16x4 b, floatx4 c) {
#if __has_builtin(__builtin_amdgcn_mfma_f32_16x16x16bf16_1k)
    return __builtin_amdgcn_mfma_f32_16x16x16bf16_1k(a, b, c, 0, 0, 0);
#else
    asm volatile("v_mfma_f32_16x16x16_bf16 %0, %1, %2, %0" : "+v"(c) : "v"(a), "v"(b));
    return c;
#endif
}

// async global->LDS, 16B per lane; lds dest = wave-uniform base + lane*16
__device__ __forceinline__ void gll16(const unsigned short* g, unsigned short* l) {
    __builtin_amdgcn_global_load_lds(
        (const __attribute__((address_space(1))) unsigned int*)(const void*)g,
        (__attribute__((address_space(3))) unsigned int*)(void*)l, 16, 0, 0);
}

// ---------------------------------------------------------------------------
// Kernel 0: fp32 -> bf16 conversion for the 3 activations + 4 weights.
// grid (4096, 7), block 256. 8 elems/thread.
// ---------------------------------------------------------------------------
__global__ __launch_bounds__(256)
void cvt7(const float* __restrict__ xq, const float* __restrict__ xk,
          const float* __restrict__ xv, const float* __restrict__ wq,
          const float* __restrict__ wk, const float* __restrict__ wv,
          const float* __restrict__ wo,
          unsigned short* __restrict__ oxq, unsigned short* __restrict__ oxk,
          unsigned short* __restrict__ oxv, unsigned short* __restrict__ owq,
          unsigned short* __restrict__ owk, unsigned short* __restrict__ owv,
          unsigned short* __restrict__ owo)
{
    const int z = blockIdx.y;
    const float* s; unsigned short* d; int n8;
    const int nx8 = (NB * SEQ * DMODEL) / 8, nw8 = (DMODEL * DMODEL) / 8;
    switch (z) {
        case 0: s = xq; d = oxq; n8 = nx8; break;
        case 1: s = xk; d = oxk; n8 = nx8; break;
        case 2: s = xv; d = oxv; n8 = nx8; break;
        case 3: s = wq; d = owq; n8 = nw8; break;
        case 4: s = wk; d = owk; n8 = nw8; break;
        case 5: s = wv; d = owv; n8 = nw8; break;
        default: s = wo; d = owo; n8 = nw8; break;
    }
    const int i = blockIdx.x * 256 + threadIdx.x;
    if (i >= n8) return;
    floatx4 a = ((const floatx4*)s)[2 * i];
    floatx4 b = ((const floatx4*)s)[2 * i + 1];
    u16x8 o = { f2bf(a[0]), f2bf(a[1]), f2bf(a[2]), f2bf(a[3]),
                f2bf(b[0]), f2bf(b[1]), f2bf(b[2]), f2bf(b[3]) };
    ((u16x8*)d)[i] = o;
}

// ---------------------------------------------------------------------------
// Kernel 1: Q/K/V projection, m97-style bf16 NT-GEMM (128x128 tile, BK=32,
// global_load_lds width=16). XCD-affinity swizzle on m-tiles.
// Outputs in FRAGMENT-READY layouts so attn fragment loads are coalesced
// (base + lane*16B), not scattered over 16 cache lines:
//   z=0: Q' [bh][s/16][kc(2)][lane(64)][8]   lane=(s%16)+16*((d%32)/8)
//   z=1: K' same as Q'
//   z=2: V' [bh][s/64][dt(4)][kc4(4)][lane(64)][4]  lane=(d%16)+16*((s%16)/4)
// grid (8, 64, 3), block 256
// ---------------------------------------------------------------------------
__global__ __launch_bounds__(256)
void proj_qkv(const unsigned short* __restrict__ Xq, const unsigned short* __restrict__ Xk,
              const unsigned short* __restrict__ Xv,
              const unsigned short* __restrict__ Wq, const unsigned short* __restrict__ Wk,
              const unsigned short* __restrict__ Wv,
              const float* __restrict__ bq, const float* __restrict__ bk,
              const float* __restrict__ bv,
              unsigned short* __restrict__ Oq, unsigned short* __restrict__ Ok,
              unsigned short* __restrict__ Ovt)
{
    const int z = blockIdx.z;
    const unsigned short* Xp = (z == 0) ? Xq : (z == 1) ? Xk : Xv;
    const unsigned short* Wp = (z == 0) ? Wq : (z == 1) ? Wk : Wv;
    const float* bp = (z == 0) ? bq : (z == 1) ? bk : bv;

    const int tid  = threadIdx.x;
    const int lane = tid & 63;
    const int wave = tid >> 6;
    const int quad = lane >> 4;
    const int lc   = lane & 15;
    const int wm   = (wave >> 1) * 64;
    const int wn   = (wave & 1) * 64;
    // XCD-affinity swizzle: xcd = lin%8; m-tiles with ty%8==xcd stay local
    const int lin = blockIdx.x + 8 * blockIdx.y;
    const int xcd = lin & 7, j = lin >> 3;
    const int m0 = (xcd + 8 * (j & 7)) * 128;
    const int n0 = (j >> 3) * 128;

    __shared__ unsigned short As[128 * 32];  // no padding: global_load_lds layout
    __shared__ unsigned short Bs[128 * 32];  // stride 64B -> 2-way banks (free)

    floatx4 acc[4][4];
#pragma unroll
    for (int i = 0; i < 4; i++)
#pragma unroll
        for (int jj = 0; jj < 4; jj++) acc[i][jj] = (floatx4){0.f, 0.f, 0.f, 0.f};

    const unsigned short* ga = Xp + (size_t)(m0 + (tid >> 2)) * DMODEL + (tid & 3) * 8;
    const unsigned short* gb = Wp + (size_t)(n0 + (tid >> 2)) * DMODEL + (tid & 3) * 8;
    unsigned short* lA = As + wave * 512;   // lane*16B appended by HW
    unsigned short* lB = Bs + wave * 512;

    for (int k0 = 0; k0 < DMODEL; k0 += 32) {
        __syncthreads();
        gll16(ga, lA);
        gll16(ga + 64 * DMODEL, lA + 2048);
        gll16(gb, lB);
        gll16(gb + 64 * DMODEL, lB + 2048);
        ga += 32; gb += 32;
        __syncthreads();

        s16x8 af[4], bf[4];
#pragma unroll
        for (int t = 0; t < 4; t++) {
            af[t] = *(const s16x8*)&As[(wm + t * 16 + lc) * 32 + quad * 8];
            bf[t] = *(const s16x8*)&Bs[(wn + t * 16 + lc) * 32 + quad * 8];
        }
#pragma unroll
        for (int tr = 0; tr < 4; tr++)
#pragma unroll
            for (int tc = 0; tc < 4; tc++)
                acc[tr][tc] = __builtin_amdgcn_mfma_f32_16x16x32_bf16(
                    af[tr], bf[tc], acc[tr][tc], 0, 0, 0);
    }

    if (z < 2) {
        unsigned short* Op = (z == 0) ? Oq : Ok;
        const float sc = (z == 0) ? SC2 : 1.0f;
#pragma unroll
        for (int tc = 0; tc < 4; tc++) {
            const int n = n0 + wn + tc * 16 + lc;
            const float bias = bp[n];
            const int h = n >> 6, dd = n & 63;
            const int kc = dd >> 5, dg = (dd & 31) >> 3, de = dd & 7;
#pragma unroll
            for (int tr = 0; tr < 4; tr++) {
#pragma unroll
                for (int r = 0; r < 4; r++) {
                    const int m = m0 + wm + tr * 16 + quad * 4 + r;
                    const int b = m >> 11, s = m & (SEQ - 1);
                    // fragment-ready: [bh][s>>4][kc][ (s&15)+16*dg ][de]
                    const size_t idx =
                        ((((size_t)(b * NH + h) * 128 + (s >> 4)) * 2 + kc) * 64
                         + (s & 15) + 16 * dg) * 8 + de;
                    Op[idx] = f2bf((acc[tr][tc][r] + bias) * sc);
                }
            }
        }
    } else {
        // V': [bh][s>>6][dt][kc4][lane][4]; lane' == lane, 8B coalesced stores
#pragma unroll
        for (int tc = 0; tc < 4; tc++) {
            const int n = n0 + wn + tc * 16 + lc;
            const float bias = bp[n];
            const int h = n >> 6, dd = n & 63;
            const int dt = dd >> 4;
#pragma unroll
            for (int tr = 0; tr < 4; tr++) {
                const int m = m0 + wm + tr * 16 + quad * 4;
                const int b = m >> 11, s = m & (SEQ - 1);
                const int kc4 = (s & 63) >> 4;
                const size_t idx =
                    (((((size_t)(b * NH + h) * 32 + (s >> 6)) * 4 + dt) * 4 + kc4) * 64
                     + (dd & 15) + 16 * ((s & 15) >> 2)) * 4;
                u16x4 pv = { f2bf(acc[tr][tc][0] + bias), f2bf(acc[tr][tc][1] + bias),
                             f2bf(acc[tr][tc][2] + bias), f2bf(acc[tr][tc][3] + bias) };
                *(u16x4*)&Ovt[idx] = pv;
            }
        }
    }
}

// ---------------------------------------------------------------------------
// Kernel 2: attention — r6 structure (64 q-rows/wave, register P path, VGPR
// ~120, no spill, XCD head-affinity swizzle) with FRAGMENT-READY Q/K/V
// layouts: every fragment load is base + lane*16B (one coalesced transaction)
// instead of 16 scattered cache lines. r6 evidence: FETCH 25 MB but dur
// unchanged at 190 us -> TA-transaction-bound, not BW-bound.
// DO NOT raise register pressure (r4/r5 spilled -> 300-400 MB scratch).
// grid (8, 64), block 256
// ---------------------------------------------------------------------------
__global__ __launch_bounds__(256, 2)
void attn2(const unsigned short* __restrict__ Qg, const unsigned short* __restrict__ Kg,
           const unsigned short* __restrict__ Vt, unsigned short* __restrict__ Og)
{
    // swizzle: lin%8 selects XCD (round-robin dispatch); give each XCD 8 heads
    const int lin = blockIdx.x + 8 * blockIdx.y;
    const int xcd = lin & 7, j = lin >> 3;
    const int bh  = xcd * 8 + (j & 7);   // 8 heads per XCD
    const int qt  = j >> 3;              // q-block 0..7 (256 rows each)
    const int b = bh >> 4, h = bh & 15;

    const int lane = threadIdx.x & 63;
    const int wave = threadIdx.x >> 6;
    const int quad = lane >> 4;
    const int lc   = lane & 15;
    const int q0   = qt * 256 + wave * 64;

    const unsigned short* Qp = Qg + ((size_t)bh * 128) * 2 * 64 * 8;
    const unsigned short* Kp = Kg + ((size_t)bh * 128) * 2 * 64 * 8;
    const unsigned short* Vp = Vt + ((size_t)bh * 32) * 4 * 4 * 64 * 4;

    // Q B-frags: [q-tile mt][k-chunk], coalesced lane*16B loads, loaded once
    s16x8 qf[4][2];
#pragma unroll
    for (int mt = 0; mt < 4; mt++)
#pragma unroll
        for (int kc = 0; kc < 2; kc++)
            qf[mt][kc] = *(const s16x8*)&Qp[((((size_t)(q0 >> 4) + mt) * 2 + kc) * 64 + lane) * 8];

    floatx4 oacc[4][4];   // O^T tiles [dt][mt]
    float rs[4] = {0.f, 0.f, 0.f, 0.f};
#pragma unroll
    for (int dt = 0; dt < 4; dt++)
#pragma unroll
        for (int mt = 0; mt < 4; mt++) oacc[dt][mt] = (floatx4){0.f, 0.f, 0.f, 0.f};

    for (int kv0 = 0; kv0 < SEQ; kv0 += 64) {
        // K A-frags: coalesced
        s16x8 kf[4][2];
#pragma unroll
        for (int nt = 0; nt < 4; nt++)
#pragma unroll
            for (int kc = 0; kc < 2; kc++)
                kf[nt][kc] = *(const s16x8*)&Kp[((((size_t)(kv0 >> 4) + nt) * 2 + kc) * 64 + lane) * 8];

        // V^T A-frags: coalesced lane*8B loads
        s16x4 vf[4][4];
#pragma unroll
        for (int dt = 0; dt < 4; dt++)
#pragma unroll
            for (int kc4 = 0; kc4 < 4; kc4++)
                vf[dt][kc4] = *(const s16x4*)&Vp[((((size_t)(kv0 >> 6) * 4 + dt) * 4 + kc4) * 64 + lane) * 4];

        // per kv-tile: scores, exp2, pack P^T B-frags
        unsigned int pj[4][4][2];   // [kv-chunk][q-tile][2]
#pragma unroll
        for (int nt = 0; nt < 4; nt++) {
            floatx4 sc[4];
#pragma unroll
            for (int mt = 0; mt < 4; mt++) sc[mt] = (floatx4){0.f, 0.f, 0.f, 0.f};
#pragma unroll
            for (int kc = 0; kc < 2; kc++)
#pragma unroll
                for (int mt = 0; mt < 4; mt++)
                    sc[mt] = __builtin_amdgcn_mfma_f32_16x16x32_bf16(
                        kf[nt][kc], qf[mt][kc], sc[mt], 0, 0, 0);
#pragma unroll
            for (int mt = 0; mt < 4; mt++) {
                float e0 = __builtin_amdgcn_exp2f(sc[mt][0]);
                float e1 = __builtin_amdgcn_exp2f(sc[mt][1]);
                float e2 = __builtin_amdgcn_exp2f(sc[mt][2]);
                float e3 = __builtin_amdgcn_exp2f(sc[mt][3]);
                rs[mt] += (e0 + e1) + (e2 + e3);
                pj[nt][mt][0] = pkbf(e0, e1);
                pj[nt][mt][1] = pkbf(e2, e3);
            }
        }

        // O^T += V^T P^T  (B operand direct from registers)
#pragma unroll
        for (int kc4 = 0; kc4 < 4; kc4++)
#pragma unroll
            for (int dt = 0; dt < 4; dt++)
#pragma unroll
                for (int mt = 0; mt < 4; mt++)
                    oacc[dt][mt] = mfma16x16x16bf(
                        vf[dt][kc4], *(const s16x4*)&pj[kc4][mt][0], oacc[dt][mt]);
    }

    // finish row sums across quads (lanes with equal lc hold same q columns)
    float inv[4];
#pragma unroll
    for (int mt = 0; mt < 4; mt++) {
        float r = rs[mt];
        r += __shfl_xor(r, 16);
        r += __shfl_xor(r, 32);
        inv[mt] = __builtin_amdgcn_rcpf(r);
    }

    // store O^T -> X[b][s][h*64+d] bf16 (packed 8B stores)
#pragma unroll
    for (int mt = 0; mt < 4; mt++) {
        const int s = q0 + mt * 16 + lc;
        const size_t base = ((size_t)(b * SEQ + s)) * DMODEL + h * DK;
#pragma unroll
        for (int dt = 0; dt < 4; dt++) {
            float v0 = oacc[dt][mt][0] * inv[mt];
            float v1 = oacc[dt][mt][1] * inv[mt];
            float v2 = oacc[dt][mt][2] * inv[mt];
            float v3 = oacc[dt][mt][3] * inv[mt];
            u32x2 pk = { pkbf(v0, v1), pkbf(v2, v3) };
            *(u32x2*)&Og[base + dt * 16 + quad * 4] = pk;
        }
    }
}

// ---------------------------------------------------------------------------
// Kernel 3: out = X @ Wo^T + bo, fp32 output. m97-style bf16 NT-GEMM.
// grid (8, 64), block 256
// ---------------------------------------------------------------------------
__global__ __launch_bounds__(256)
void out_proj(const unsigned short* __restrict__ Xg, const unsigned short* __restrict__ Wo,
              const float* __restrict__ bo, float* __restrict__ Out)
{
    const int tid  = threadIdx.x;
    const int lane = tid & 63;
    const int wave = tid >> 6;
    const int quad = lane >> 4;
    const int lc   = lane & 15;
    const int wm   = (wave >> 1) * 64;
    const int wn   = (wave & 1) * 64;
    const int lin = blockIdx.x + 8 * blockIdx.y;
    const int xcd = lin & 7, j = lin >> 3;
    const int m0 = (xcd + 8 * (j & 7)) * 128;
    const int n0 = (j >> 3) * 128;

    __shared__ unsigned short As[128 * 32];
    __shared__ unsigned short Bs[128 * 32];

    floatx4 acc[4][4];
#pragma unroll
    for (int i = 0; i < 4; i++)
#pragma unroll
        for (int jj = 0; jj < 4; jj++) acc[i][jj] = (floatx4){0.f, 0.f, 0.f, 0.f};

    const unsigned short* ga = Xg + (size_t)(m0 + (tid >> 2)) * DMODEL + (tid & 3) * 8;
    const unsigned short* gb = Wo + (size_t)(n0 + (tid >> 2)) * DMODEL + (tid & 3) * 8;
    unsigned short* lA = As + wave * 512;
    unsigned short* lB = Bs + wave * 512;

    for (int k0 = 0; k0 < DMODEL; k0 += 32) {
        __syncthreads();
        gll16(ga, lA);
        gll16(ga + 64 * DMODEL, lA + 2048);
        gll16(gb, lB);
        gll16(gb + 64 * DMODEL, lB + 2048);
        ga += 32; gb += 32;
        __syncthreads();

        s16x8 af[4], bf[4];
#pragma unroll
        for (int t = 0; t < 4; t++) {
            af[t] = *(const s16x8*)&As[(wm + t * 16 + lc) * 32 + quad * 8];
            bf[t] = *(const s16x8*)&Bs[(wn + t * 16 + lc) * 32 + quad * 8];
        }
#pragma unroll
        for (int tr = 0; tr < 4; tr++)
#pragma unroll
            for (int tc = 0; tc < 4; tc++)
                acc[tr][tc] = __builtin_amdgcn_mfma_f32_16x16x32_bf16(
                    af[tr], bf[tc], acc[tr][tc], 0, 0, 0);
    }

#pragma unroll
    for (int tc = 0; tc < 4; tc++) {
        const int n = n0 + wn + tc * 16 + lc;
        const float bias = bo[n];
#pragma unroll
        for (int tr = 0; tr < 4; tr++) {
#pragma unroll
            for (int r = 0; r < 4; r++) {
                const int m = m0 + wm + tr * 16 + quad * 4 + r;
                Out[(size_t)m * DMODEL + n] = acc[tr][tc][r] + bias;
            }
        }
    }
}

// ---------------------------------------------------------------------------
extern "C" void kernel_launch(void* const* d_in, const int* in_sizes, int n_in,
                              void* d_out, int out_size, void* d_ws, size_t ws_size,
                              hipStream_t stream)
{
    const float* q  = (const float*)d_in[0];
    const float* k  = (const float*)d_in[1];
    const float* v  = (const float*)d_in[2];
    const float* Wq = (const float*)d_in[3];
    const float* bq = (const float*)d_in[4];
    const float* Wk = (const float*)d_in[5];
    const float* bk = (const float*)d_in[6];
    const float* Wv = (const float*)d_in[7];
    const float* bv = (const float*)d_in[8];
    const float* Wo = (const float*)d_in[9];
    const float* bo = (const float*)d_in[10];

    const size_t NX = (size_t)NB * SEQ * DMODEL;   // 8,388,608
    const size_t NW = (size_t)DMODEL * DMODEL;     // 1,048,576
    unsigned short* xq_bf = (unsigned short*)d_ws;
    unsigned short* xk_bf = xq_bf + NX;
    unsigned short* xv_bf = xk_bf + NX;
    unsigned short* wq_bf = xv_bf + NX;
    unsigned short* wk_bf = wq_bf + NW;
    unsigned short* wv_bf = wk_bf + NW;
    unsigned short* wo_bf = wv_bf + NW;
    unsigned short* Qb    = wo_bf + NW;
    unsigned short* Kb    = Qb + NX;
    unsigned short* Vtb   = Kb + NX;
    unsigned short* Xa    = xq_bf;   // alias: xq_bf dead after proj_qkv
    // footprint: 3*NX + 4*NW + 3*NX = 104 MB

    dim3 blk(256);
    cvt7<<<dim3(4096, 7), blk, 0, stream>>>(q, k, v, Wq, Wk, Wv, Wo,
                                            xq_bf, xk_bf, xv_bf,
                                            wq_bf, wk_bf, wv_bf, wo_bf);
    proj_qkv<<<dim3(8, 64, 3), blk, 0, stream>>>(xq_bf, xk_bf, xv_bf,
                                                 wq_bf, wk_bf, wv_bf,
                                                 bq, bk, bv, Qb, Kb, Vtb);
    attn2<<<dim3(8, 64), blk, 0, stream>>>(Qb, Kb, Vtb, Xa);
    out_proj<<<dim3(8, 64), blk, 0, stream>>>(Xa, wo_bf, bo, (float*)d_out);
}